// Round 7
// baseline (189.774 us; speedup 1.0000x reference)
//
#include <hip/hip_runtime.h>
#include <math.h>

#define BB 8
#define TT 4096
#define DD 2048

typedef float v4f __attribute__((ext_vector_type(4)));

__device__ __forceinline__ float gelu_fast(float x) {
    // gelu(x) = x * sigmoid(2c*(x + 0.044715 x^3)); saturates correctly.
    const float c1 = 1.5957691216057308f;    // 2*sqrt(2/pi)
    const float c2 = 0.07135481282556483f;   // 2c*0.044715
    float e = __expf(-x * fmaf(c2, x * x, c1));
    return x * __builtin_amdgcn_rcpf(1.0f + e);
}

// ---------------- K1: sim[b,t] (one wave per (b,t) row; pure read stream) --
__global__ __launch_bounds__(256) void k_sims(
    const float* __restrict__ x,        // [B,T,D]
    const float* __restrict__ pos_buf,  // [T,D]
    float* __restrict__ sims)           // [T*8]  layout t*8+b
{
    const int pair = blockIdx.x * 4 + (threadIdx.x >> 6);  // 0..32767
    const int lane = threadIdx.x & 63;
    const int t    = pair >> 3;
    const int b    = pair & 7;

    const float* xr = x       + ((size_t)b * TT + t) * DD + lane * 4;
    const float* pr = pos_buf + (size_t)t * DD + lane * 4;

    // issue all 16 loads back-to-back (MLP)
    v4f xv[8], pv[8];
#pragma unroll
    for (int c = 0; c < 8; ++c) xv[c] = *(const v4f*)(xr + c * 256);
#pragma unroll
    for (int c = 0; c < 8; ++c) pv[c] = *(const v4f*)(pr + c * 256);

    float dot = 0.f, yn2 = 0.f, pn2 = 0.f;
#pragma unroll
    for (int c = 0; c < 8; ++c) {
        v4f v = xv[c];
        v.x = gelu_fast(v.x); v.y = gelu_fast(v.y);
        v.z = gelu_fast(v.z); v.w = gelu_fast(v.w);
        const v4f p = pv[c];
        dot += v.x * p.x + v.y * p.y + v.z * p.z + v.w * p.w;
        yn2 += v.x * v.x + v.y * v.y + v.z * v.z + v.w * v.w;
        pn2 += p.x * p.x + p.y * p.y + p.z * p.z + p.w * p.w;
    }
#pragma unroll
    for (int off = 32; off; off >>= 1) {
        dot += __shfl_xor(dot, off);
        yn2 += __shfl_xor(yn2, off);
        pn2 += __shfl_xor(pn2, off);
    }
    if (lane == 0) {
        const float yn = fmaxf(sqrtf(yn2), 1e-12f);
        const float pn = fmaxf(sqrtf(pn2), 1e-12f);
        sims[pair] = dot / (yn * pn);
    }
}

// ---------------- K1.5: gate[b,t] from sims (tiny) ------------------------
__global__ __launch_bounds__(256) void k_gates(
    const float* __restrict__ sims,       // [T*8]
    const float* __restrict__ pos_facil,  // [T]
    const float* __restrict__ log_k_pos,  // [1]
    float* __restrict__ gates)            // [T*8]
{
    const int t = blockIdx.x * 256 + threadIdx.x;  // 4096 threads
    const float kp = fminf(fmaxf(__expf(log_k_pos[0]), 0.01f), 5.0f);

    float s[BB];
    float simsum = 0.f;
#pragma unroll
    for (int b = 0; b < BB; ++b) {
        s[b] = sims[t * 8 + b];
        simsum += s[b];
    }
    const bool  fire  = (simsum * 0.125f) > 0.85f;
    const float pf    = pos_facil[t];
    const float facil = fire ? fminf(pf * 2.0f, 16.0f) : pf;
#pragma unroll
    for (int b = 0; b < BB; ++b)
        gates[t * 8 + b] = fminf(1.0f + kp * (facil - 1.0f) * s[b], 8.0f);
}

// ---------------- K2: out = gelu(x) * gate (pure elementwise stream) ------
__global__ __launch_bounds__(512) void k_apply(
    const float* __restrict__ x,      // [B,T,D]
    const float* __restrict__ gates,  // [T*8]
    float* __restrict__ out)          // [B,T,D]
{
    const int t    = blockIdx.x;
    const int lane = threadIdx.x & 63;
    const int b    = threadIdx.x >> 6;

    const float g = gates[t * 8 + b];   // wave-uniform -> scalar load

    const float* xr = x   + ((size_t)b * TT + t) * DD + lane * 4;
    float*       po = out + ((size_t)b * TT + t) * DD + lane * 4;

    v4f xv[8];
#pragma unroll
    for (int c = 0; c < 8; ++c) xv[c] = *(const v4f*)(xr + c * 256);
#pragma unroll
    for (int c = 0; c < 8; ++c) {
        v4f o = xv[c];
        o.x = gelu_fast(o.x) * g;
        o.y = gelu_fast(o.y) * g;
        o.z = gelu_fast(o.z) * g;
        o.w = gelu_fast(o.w) * g;
        *(v4f*)(po + c * 256) = o;
    }
}

extern "C" void kernel_launch(void* const* d_in, const int* in_sizes, int n_in,
                              void* d_out, int out_size, void* d_ws, size_t ws_size,
                              hipStream_t stream) {
    const float* x          = (const float*)d_in[0];
    const float* log_k_pos  = (const float*)d_in[1];
    const float* pos_buf    = (const float*)d_in[2];
    const float* pos_facil  = (const float*)d_in[3];
    float* out              = (float*)d_out;

    float* sims  = (float*)d_ws;                 // 32768 floats = 128 KB
    float* gates = sims + (size_t)TT * BB;       // next 128 KB

    k_sims <<<dim3((TT * BB) / 4), dim3(256), 0, stream>>>(x, pos_buf, sims);
    k_gates<<<dim3(TT / 256),      dim3(256), 0, stream>>>(sims, pos_facil,
                                                           log_k_pos, gates);
    k_apply<<<dim3(TT),            dim3(512), 0, stream>>>(x, gates, out);
}

// Round 8
// 143.671 us; speedup vs baseline: 1.3209x; 1.3209x over previous
//
#include <hip/hip_runtime.h>
#include <math.h>

#define BB 8
#define TT 4096
#define DD 2048
#define THREADS 512           // 8 waves; wave w owns batch row b=w
#define NT 4                  // t-steps per persistent block
#define NBLK (TT / NT)        // 1024 blocks -> target 3 resident/CU

typedef float v4f __attribute__((ext_vector_type(4)));

__device__ __forceinline__ float gelu_fast(float x) {
    // gelu(x) = x * sigmoid(2c*(x + 0.044715 x^3)); saturates correctly.
    const float c1 = 1.5957691216057308f;    // 2*sqrt(2/pi)
    const float c2 = 0.07135481282556483f;   // 2c*0.044715
    float e = __expf(-x * fmaf(c2, x * x, c1));
    return x * __builtin_amdgcn_rcpf(1.0f + e);
}

// One t-step. CUR holds x(t) (prefetched last step). Prefetches x(t+1)->NXT.
// pos row is loaded just-in-time (L1-resident: 8 waves share it). Raw
// s_barrier + lgkmcnt-only drain keeps x-prefetch in flight across the sync.
__device__ __forceinline__ void do_step(
    const float* __restrict__ xp,        // this wave's x row base for t
    const float* __restrict__ pp,        // pos row base for t (lane offset in)
    const float* __restrict__ pos_facil, float* __restrict__ op,
    int t, int par, bool last, int lane, int wave, float kp,
    v4f (&CUR)[8], v4f (&NXT)[8],
    float (&s_red)[2][17])
{
    // 1) prefetch next x row for this wave (consumed NEXT step)
    if (!last) {
#pragma unroll
        for (int c = 0; c < 8; ++c)
            NXT[c] = *(const v4f*)(xp + DD + c * 256);
    }

    // 2) gelu CUR in place + partial dot / |y|^2 / |p|^2 (pos JIT from L1)
    float dot = 0.f, yn2 = 0.f, pn2 = 0.f;
#pragma unroll
    for (int c = 0; c < 8; ++c) {
        const v4f p = *(const v4f*)(pp + c * 256);
        v4f v = CUR[c];
        v.x = gelu_fast(v.x); v.y = gelu_fast(v.y);
        v.z = gelu_fast(v.z); v.w = gelu_fast(v.w);
        CUR[c] = v;
        dot += v.x * p.x + v.y * p.y + v.z * p.z + v.w * p.w;
        yn2 += v.x * v.x + v.y * v.y + v.z * v.z + v.w * v.w;
        pn2 += p.x * p.x + p.y * p.y + p.z * p.z + p.w * p.w;
    }

    // 3) wave butterfly (3 values x 6 rounds), cross-wave via LDS
#pragma unroll
    for (int off = 32; off; off >>= 1) {
        dot += __shfl_xor(dot, off);
        yn2 += __shfl_xor(yn2, off);
        pn2 += __shfl_xor(pn2, off);
    }
    if (lane == 0) {
        s_red[par][wave]      = dot;
        s_red[par][BB + wave] = yn2;
        if (wave == 0) s_red[par][16] = pn2;
    }
    // LDS-only drain + RAW barrier: prefetched global loads stay in flight
    asm volatile("s_waitcnt lgkmcnt(0)" ::: "memory");
    __builtin_amdgcn_s_barrier();
    asm volatile("" ::: "memory");

    // 4) gate from the 17 LDS scalars (redundant per thread)
    const float pnn = fmaxf(sqrtf(s_red[par][16]), 1e-12f);
    float simsum = 0.f, simw = 0.f;
#pragma unroll
    for (int b = 0; b < BB; ++b) {
        const float s = s_red[par][b] *
            __builtin_amdgcn_rcpf(fmaxf(sqrtf(s_red[par][BB + b]), 1e-12f) * pnn);
        simsum += s;
        if (b == wave) simw = s;
    }
    const bool  fire  = (simsum * 0.125f) > 0.85f;
    const float pf    = pos_facil[t];
    const float facil = fire ? fminf(pf * 2.0f, 16.0f) : pf;
    const float g     = fminf(1.0f + kp * (facil - 1.0f) * simw, 8.0f);

    // 5) gated store of this wave's row
#pragma unroll
    for (int c = 0; c < 8; ++c) {
        v4f o = CUR[c];
        o.x *= g; o.y *= g; o.z *= g; o.w *= g;
        *(v4f*)(op + c * 256) = o;
    }
}

__global__ __launch_bounds__(THREADS, 6) void gelu275_fused(
    const float* __restrict__ x,          // [B,T,D]
    const float* __restrict__ log_k_pos,  // [1]
    const float* __restrict__ pos_buf,    // [T,D]
    const float* __restrict__ pos_facil,  // [T]
    float* __restrict__ out)              // [B,T,D]
{
    const int tid  = threadIdx.x;
    const int lane = tid & 63;
    const int wave = tid >> 6;            // == batch row b
    const int t0   = blockIdx.x * NT;

    __shared__ float s_red[2][17];        // parity-double-buffered partials

    const float kp   = fminf(fmaxf(__expf(log_k_pos[0]), 0.01f), 5.0f);
    const int   base = lane * 4;

    const float* xp = x       + ((size_t)wave * TT + t0) * DD + base;
    const float* pp = pos_buf + (size_t)t0 * DD + base;
    float*       op = out     + ((size_t)wave * TT + t0) * DD + base;

    v4f A[8], B[8];

    // prologue: x(t0) -> A
#pragma unroll
    for (int c = 0; c < 8; ++c) A[c] = *(const v4f*)(xp + c * 256);

#pragma unroll
    for (int i = 0; i < NT; i += 2) {
        do_step(xp, pp, pos_facil, op, t0 + i, 0, false,
                lane, wave, kp, A, B, s_red);
        xp += DD; pp += DD; op += DD;
        do_step(xp, pp, pos_facil, op, t0 + i + 1, 1, (i + 2 >= NT),
                lane, wave, kp, B, A, s_red);
        xp += DD; pp += DD; op += DD;
    }
}

extern "C" void kernel_launch(void* const* d_in, const int* in_sizes, int n_in,
                              void* d_out, int out_size, void* d_ws, size_t ws_size,
                              hipStream_t stream) {
    const float* x          = (const float*)d_in[0];
    const float* log_k_pos  = (const float*)d_in[1];
    const float* pos_buf    = (const float*)d_in[2];
    const float* pos_facil  = (const float*)d_in[3];
    float* out              = (float*)d_out;

    dim3 grid(NBLK);
    dim3 block(THREADS);
    gelu275_fused<<<grid, block, 0, stream>>>(x, log_k_pos, pos_buf, pos_facil, out);
}

// Round 9
// 130.681 us; speedup vs baseline: 1.4522x; 1.0994x over previous
//
#include <hip/hip_runtime.h>
#include <math.h>

#define BB 8
#define TT 4096
#define DD 2048
#define THREADS 1024          // 16 waves; wave = (b = w&7, half = w>>3)
#define NT 8                  // t-steps per block
#define NBLK (TT / NT)        // 512 blocks

typedef float v4f __attribute__((ext_vector_type(4)));

__device__ __forceinline__ float gelu_fast(float x) {
    // gelu(x) = x * sigmoid(2c*(x + 0.044715 x^3)); saturates correctly.
    const float c1 = 1.5957691216057308f;    // 2*sqrt(2/pi)
    const float c2 = 0.07135481282556483f;   // 2c*0.044715
    float e = __expf(-x * fmaf(c2, x * x, c1));
    return x * __builtin_amdgcn_rcpf(1.0f + e);
}

__global__ __launch_bounds__(THREADS, 4) void gelu275_fused(
    const float* __restrict__ x,          // [B,T,D]
    const float* __restrict__ log_k_pos,  // [1]
    const float* __restrict__ pos_buf,    // [T,D]
    const float* __restrict__ pos_facil,  // [T]
    float* __restrict__ out)              // [B,T,D]
{
    const int tid  = threadIdx.x;
    const int lane = tid & 63;
    const int wave = tid >> 6;
    const int b    = wave & 7;            // batch row
    const int h    = wave >> 3;           // 0 = low half of D, 1 = high half
    const int t0   = blockIdx.x * NT;

    // per-wave partials: dot[16] | yn2[16] | pn2[16], parity double-buffered
    __shared__ float s_red[2][48];

    const float kp   = fminf(fmaxf(__expf(log_k_pos[0]), 0.01f), 5.0f);
    const int   base = h * 1024 + lane * 4;

    const float* xp = x       + ((size_t)b * TT + t0) * DD + base;
    const float* pp = pos_buf + (size_t)t0 * DD + base;
    float*       op = out     + ((size_t)b * TT + t0) * DD + base;

    v4f X[3][4];                          // 3-deep rotation, 4 chunks/half-row
    v4f P[4];                             // pos half-row, 1-step prefetch

    // prologue: x(t0)->X0, x(t0+1)->X1, pos(t0)->P
#pragma unroll
    for (int c = 0; c < 4; ++c) X[0][c] = *(const v4f*)(xp + c * 256);
#pragma unroll
    for (int c = 0; c < 4; ++c) X[1][c] = *(const v4f*)(xp + DD + c * 256);
#pragma unroll
    for (int c = 0; c < 4; ++c) P[c]    = *(const v4f*)(pp + c * 256);

#pragma unroll
    for (int i = 0; i < NT; ++i) {
        const int cur = i % 3;
        const int nxt = (i + 2) % 3;
        const int par = i & 1;

        // 1) prefetch x(t+2) — keeps ~2 steps of reads in flight
        if (i + 2 < NT) {
#pragma unroll
            for (int c = 0; c < 4; ++c)
                X[nxt][c] = *(const v4f*)(xp + (size_t)(i + 2) * DD + c * 256);
        }

        // 2) gelu in place + partial dot / |y|^2 / |p|^2 on this half-row
        float dot = 0.f, yn2 = 0.f, pn2 = 0.f;
#pragma unroll
        for (int c = 0; c < 4; ++c) {
            v4f v = X[cur][c];
            const v4f p = P[c];
            v.x = gelu_fast(v.x); v.y = gelu_fast(v.y);
            v.z = gelu_fast(v.z); v.w = gelu_fast(v.w);
            X[cur][c] = v;
            dot += v.x * p.x + v.y * p.y + v.z * p.z + v.w * p.w;
            yn2 += v.x * v.x + v.y * v.y + v.z * v.z + v.w * v.w;
            pn2 += p.x * p.x + p.y * p.y + p.z * p.z + p.w * p.w;
        }

        // 3) refill P with pos(t+1) (P regs dead; full step of latency cover)
        if (i + 1 < NT) {
#pragma unroll
            for (int c = 0; c < 4; ++c)
                P[c] = *(const v4f*)(pp + (size_t)(i + 1) * DD + c * 256);
        }

        // 4) wave butterfly (3 values x 6 rounds)
#pragma unroll
        for (int off = 32; off; off >>= 1) {
            dot += __shfl_xor(dot, off);
            yn2 += __shfl_xor(yn2, off);
            pn2 += __shfl_xor(pn2, off);
        }
        if (lane == 0) {
            s_red[par][wave]      = dot;
            s_red[par][16 + wave] = yn2;
            s_red[par][32 + wave] = pn2;
        }
        // LDS-only drain + RAW barrier: x/pos prefetches stay in flight
        asm volatile("s_waitcnt lgkmcnt(0)" ::: "memory");
        __builtin_amdgcn_s_barrier();
        asm volatile("" ::: "memory");

        // 5) gates from LDS partials (combine the two half-rows per b)
        const float pn2t = s_red[par][32] + s_red[par][40];
        const float pnn  = fmaxf(sqrtf(pn2t), 1e-12f);
        float simsum = 0.f, simb = 0.f;
#pragma unroll
        for (int bb = 0; bb < BB; ++bb) {
            const float dt = s_red[par][bb]      + s_red[par][8 + bb];
            const float yt = s_red[par][16 + bb] + s_red[par][24 + bb];
            const float s  = dt *
                __builtin_amdgcn_rcpf(fmaxf(sqrtf(yt), 1e-12f) * pnn);
            simsum += s;
            if (bb == b) simb = s;
        }
        const bool  fire  = (simsum * 0.125f) > 0.85f;
        const float pf    = pos_facil[t0 + i];
        const float facil = fire ? fminf(pf * 2.0f, 16.0f) : pf;
        const float g     = fminf(1.0f + kp * (facil - 1.0f) * simb, 8.0f);

        // 6) gated store of this half-row
#pragma unroll
        for (int c = 0; c < 4; ++c) {
            v4f o = X[cur][c];
            o.x *= g; o.y *= g; o.z *= g; o.w *= g;
            *(v4f*)(op + (size_t)i * DD + c * 256) = o;
        }
    }
}

extern "C" void kernel_launch(void* const* d_in, const int* in_sizes, int n_in,
                              void* d_out, int out_size, void* d_ws, size_t ws_size,
                              hipStream_t stream) {
    const float* x          = (const float*)d_in[0];
    const float* log_k_pos  = (const float*)d_in[1];
    const float* pos_buf    = (const float*)d_in[2];
    const float* pos_facil  = (const float*)d_in[3];
    float* out              = (float*)d_out;

    dim3 grid(NBLK);
    dim3 block(THREADS);
    gelu275_fused<<<grid, block, 0, stream>>>(x, log_k_pos, pos_buf, pos_facil, out);
}

// Round 10
// 120.739 us; speedup vs baseline: 1.5718x; 1.0823x over previous
//
#include <hip/hip_runtime.h>
#include <math.h>

#define BB 8
#define TT 4096
#define DD 2048
#define THREADS 512           // 8 waves; wave w owns batch row b=w
#define NT 8                  // t-steps per block
#define NBLK (TT / NT)        // 512 blocks -> 1 resident/CU (LDS-bound), 2 sequential
#define SMEM_BYTES ((2 * (BB * DD + DD)) * 4)   // 147456 B: 2 x-tiles + 2 pos rows

typedef float v4f __attribute__((ext_vector_type(4)));

__device__ __forceinline__ float gelu_fast(float x) {
    // gelu(x) = x * sigmoid(2c*(x + 0.044715 x^3)); saturates correctly.
    const float c1 = 1.5957691216057308f;    // 2*sqrt(2/pi)
    const float c2 = 0.07135481282556483f;   // 2c*0.044715
    float e = __expf(-x * fmaf(c2, x * x, c1));
    return x * __builtin_amdgcn_rcpf(1.0f + e);
}

// async global->LDS, 16B per lane; LDS dest is wave-uniform base + lane*16
__device__ __forceinline__ void gl2lds(const float* g, float* l) {
    __builtin_amdgcn_global_load_lds(
        (const __attribute__((address_space(1))) void*)g,
        (__attribute__((address_space(3))) void*)l, 16, 0, 0);
}

__global__ __launch_bounds__(THREADS, 2) void gelu275_fused(
    const float* __restrict__ x,          // [B,T,D]
    const float* __restrict__ log_k_pos,  // [1]
    const float* __restrict__ pos_buf,    // [T,D]
    const float* __restrict__ pos_facil,  // [T]
    float* __restrict__ out)              // [B,T,D]
{
    extern __shared__ __align__(16) float smem[];
    // layout: xbuf0[8][2048] | xbuf1[8][2048] | pbuf0[2048] | pbuf1[2048]
    float* const xbuf0 = smem;
    float* const xbuf1 = smem + BB * DD;
    float* const pbuf0 = smem + 2 * BB * DD;
    float* const pbuf1 = pbuf0 + DD;
    __shared__ float s_red[2][17];        // parity-double-buffered partials

    const int tid  = threadIdx.x;
    const int lane = tid & 63;
    const int wave = tid >> 6;            // == batch row b
    const int t0   = blockIdx.x * NT;
    const int base = lane * 4;

    const float kp = fminf(fmaxf(__expf(log_k_pos[0]), 0.01f), 5.0f);
    // hoist facil loads (s_loads) so per-step VMEM count is exactly 9+8
    float pfv[NT];
#pragma unroll
    for (int i = 0; i < NT; ++i) pfv[i] = pos_facil[t0 + i];

    // prologue: stage tile 0 into buffer 0 (9 global_load_lds per wave)
    {
        const float* xrow = x + ((size_t)wave * TT + t0) * DD;
#pragma unroll
        for (int c = 0; c < 8; ++c)
            gl2lds(xrow + c * 256 + base, xbuf0 + wave * DD + c * 256);
        gl2lds(pos_buf + (size_t)t0 * DD + wave * 256 + base,
               pbuf0 + wave * 256);
    }

#pragma unroll
    for (int i = 0; i < NT; ++i) {
        float* const xb = (i & 1) ? xbuf1 : xbuf0;
        float* const pb = (i & 1) ? pbuf1 : pbuf0;

        // --- top: own tile-i loads retired (counted wait keeps the 8 prior
        //     stores in flight), then barrier for cross-wave LDS visibility
        if (i == 0) { asm volatile("s_waitcnt vmcnt(0)" ::: "memory"); }
        else        { asm volatile("s_waitcnt vmcnt(8)" ::: "memory"); }
        __builtin_amdgcn_s_barrier();
        asm volatile("" ::: "memory");

        // --- issue tile i+1 prefetch into the other buffer (zero VGPR cost)
        if (i + 1 < NT) {
            float* const xn = (i & 1) ? xbuf0 : xbuf1;
            float* const pn = (i & 1) ? pbuf0 : pbuf1;
            const float* xrow = x + ((size_t)wave * TT + (t0 + i + 1)) * DD;
#pragma unroll
            for (int c = 0; c < 8; ++c)
                gl2lds(xrow + c * 256 + base, xn + wave * DD + c * 256);
            gl2lds(pos_buf + (size_t)(t0 + i + 1) * DD + wave * 256 + base,
                   pn + wave * 256);
        }

        // --- compute: read own row + pos from LDS, gelu, partials
        v4f Y[8];
        float dot = 0.f, yn2 = 0.f, pn2 = 0.f;
#pragma unroll
        for (int c = 0; c < 8; ++c) {
            v4f v       = *(const v4f*)(xb + wave * DD + c * 256 + base);
            const v4f p = *(const v4f*)(pb + c * 256 + base);
            v.x = gelu_fast(v.x); v.y = gelu_fast(v.y);
            v.z = gelu_fast(v.z); v.w = gelu_fast(v.w);
            Y[c] = v;
            dot += v.x * p.x + v.y * p.y + v.z * p.z + v.w * p.w;
            yn2 += v.x * v.x + v.y * v.y + v.z * v.z + v.w * v.w;
            pn2 += p.x * p.x + p.y * p.y + p.z * p.z + p.w * p.w;
        }

        // --- wave butterfly (3 values x 6 rounds), cross-wave via LDS
#pragma unroll
        for (int off = 32; off; off >>= 1) {
            dot += __shfl_xor(dot, off);
            yn2 += __shfl_xor(yn2, off);
            pn2 += __shfl_xor(pn2, off);
        }
        if (lane == 0) {
            s_red[i & 1][wave]     = dot;
            s_red[i & 1][8 + wave] = yn2;
            if (wave == 0) s_red[i & 1][16] = pn2;
        }
        // LDS-only drain + raw barrier: prefetched tile stays in flight
        asm volatile("s_waitcnt lgkmcnt(0)" ::: "memory");
        __builtin_amdgcn_s_barrier();
        asm volatile("" ::: "memory");

        // --- gate from the 17 LDS scalars (redundant per thread)
        const float pnn = fmaxf(sqrtf(s_red[i & 1][16]), 1e-12f);
        float simsum = 0.f, simw = 0.f;
#pragma unroll
        for (int bb = 0; bb < BB; ++bb) {
            const float s = s_red[i & 1][bb] *
                __builtin_amdgcn_rcpf(
                    fmaxf(sqrtf(s_red[i & 1][8 + bb]), 1e-12f) * pnn);
            simsum += s;
            if (bb == wave) simw = s;
        }
        const bool  fire  = (simsum * 0.125f) > 0.85f;
        const float pf    = pfv[i];
        const float facil = fire ? fminf(pf * 2.0f, 16.0f) : pf;
        const float g     = fminf(1.0f + kp * (facil - 1.0f) * simw, 8.0f);

        // --- gated store of this wave's row (exactly 8 VMEM stores/wave)
        float* orow = out + ((size_t)wave * TT + (t0 + i)) * DD + base;
#pragma unroll
        for (int c = 0; c < 8; ++c) {
            v4f o = Y[c];
            o.x *= g; o.y *= g; o.z *= g; o.w *= g;
            *(v4f*)(orow + c * 256) = o;
        }
    }
}

extern "C" void kernel_launch(void* const* d_in, const int* in_sizes, int n_in,
                              void* d_out, int out_size, void* d_ws, size_t ws_size,
                              hipStream_t stream) {
    const float* x          = (const float*)d_in[0];
    const float* log_k_pos  = (const float*)d_in[1];
    const float* pos_buf    = (const float*)d_in[2];
    const float* pos_facil  = (const float*)d_in[3];
    float* out              = (float*)d_out;

    // allow >64KB dynamic LDS (idempotent; set on first (non-captured) call)
    (void)hipFuncSetAttribute((const void*)gelu275_fused,
                              hipFuncAttributeMaxDynamicSharedMemorySize,
                              SMEM_BYTES);

    dim3 grid(NBLK);
    dim3 block(THREADS);
    gelu275_fused<<<grid, block, SMEM_BYTES, stream>>>(
        x, log_k_pos, pos_buf, pos_facil, out);
}